// Round 2
// baseline (16633.194 us; speedup 1.0000x reference)
//
#include <hip/hip_runtime.h>
#include <hip/hip_bf16.h>

// Problem constants
#define T_LEN 2048
#define E_DIM 512
#define H_DIM 256
#define K_TAG 48
#define START_TAG 46
#define END_TAG 47
#define NEG_VAL -10000.0f

// ---------------------------------------------------------------------------
// GEMM: out[d][t][row] = dot(A[t][0:512], W[d*1024+row][0:512]) + bih[n]+bhh[n]
// ---------------------------------------------------------------------------
__global__ __launch_bounds__(256) void gemm_xg(
    const float* __restrict__ Abase, const int* __restrict__ sent,
    const float* __restrict__ Bw, const float* __restrict__ bih,
    const float* __restrict__ bhh, float* __restrict__ out, int useGather)
{
    __shared__ float As[16][68];
    __shared__ float Bs[16][68];
    const int tx = threadIdx.x & 15, ty = threadIdx.x >> 4;
    const int t0 = blockIdx.y * 64, n0 = blockIdx.x * 64;
    const int r  = threadIdx.x >> 2;        // 0..63
    const int kq = (threadIdx.x & 3) * 4;   // 0,4,8,12
    const float* arow;
    if (useGather) arow = Abase + (size_t)sent[t0 + r] * 512 + kq;
    else           arow = Abase + (size_t)(t0 + r) * 512 + kq;
    const float* brow = Bw + (size_t)(n0 + r) * 512 + kq;

    float acc[4][4];
#pragma unroll
    for (int i = 0; i < 4; i++)
#pragma unroll
        for (int j = 0; j < 4; j++) acc[i][j] = 0.f;

    for (int k0 = 0; k0 < 512; k0 += 16) {
        float4 a4 = *(const float4*)(arow + k0);
        float4 b4 = *(const float4*)(brow + k0);
        __syncthreads();
        As[kq+0][r] = a4.x; As[kq+1][r] = a4.y; As[kq+2][r] = a4.z; As[kq+3][r] = a4.w;
        Bs[kq+0][r] = b4.x; Bs[kq+1][r] = b4.y; Bs[kq+2][r] = b4.z; Bs[kq+3][r] = b4.w;
        __syncthreads();
#pragma unroll
        for (int k = 0; k < 16; k++) {
            float4 av = *(const float4*)&As[k][ty*4];
            float4 bv = *(const float4*)&Bs[k][tx*4];
            acc[0][0] = fmaf(av.x, bv.x, acc[0][0]); acc[0][1] = fmaf(av.x, bv.y, acc[0][1]);
            acc[0][2] = fmaf(av.x, bv.z, acc[0][2]); acc[0][3] = fmaf(av.x, bv.w, acc[0][3]);
            acc[1][0] = fmaf(av.y, bv.x, acc[1][0]); acc[1][1] = fmaf(av.y, bv.y, acc[1][1]);
            acc[1][2] = fmaf(av.y, bv.z, acc[1][2]); acc[1][3] = fmaf(av.y, bv.w, acc[1][3]);
            acc[2][0] = fmaf(av.z, bv.x, acc[2][0]); acc[2][1] = fmaf(av.z, bv.y, acc[2][1]);
            acc[2][2] = fmaf(av.z, bv.z, acc[2][2]); acc[2][3] = fmaf(av.z, bv.w, acc[2][3]);
            acc[3][0] = fmaf(av.w, bv.x, acc[3][0]); acc[3][1] = fmaf(av.w, bv.y, acc[3][1]);
            acc[3][2] = fmaf(av.w, bv.z, acc[3][2]); acc[3][3] = fmaf(av.w, bv.w, acc[3][3]);
        }
    }
#pragma unroll
    for (int i = 0; i < 4; i++) {
        int t = t0 + ty*4 + i;
#pragma unroll
        for (int j = 0; j < 4; j++) {
            int n = n0 + tx*4 + j;
            float b = bih[n] + bhh[n];
            out[((size_t)((n >> 10) * 2048 + t) << 10) + (n & 1023)] = acc[i][j] + b;
        }
    }
}

// ---------------------------------------------------------------------------
// LSTM recurrence. Grid = 64 blocks; a LEADER-DECIDED rendezvous picks 8
// WORKERS that all live on ONE XCD, so the per-step h exchange is a shared-L2
// round trip (~250 cyc, sc0 load/store) instead of the Infinity-Cache round
// trip (~600-900 cyc) that agent-scope atomics pay when the 8 blocks land
// round-robin on 8 XCDs.
//
// Hang-safety design (why the protocol looks like this):
//  * Every block posts its XCC_ID tag; ONLY block 0 collects, with a BOUNDED
//    spin. Block 0 then ALWAYS publishes a decision word (mask, or 0 =
//    fallback). All other blocks wait only on that decision — live because
//    block 0 is in the same 64-block dispatch (64 blks x 8 waves always fit
//    on 256 CUs) and its publish is unconditional.
//  * One consistent decision => worker set is exactly 8, no dup/missing.
//  * Fast poll has a cumulative budget; on exhaustion it stickily falls back
//    to agent loads. Publishers dual-store (sc0 + agent), so the agent path
//    is always valid. Worst case is bounded extra latency, never a hang.
//
// Worker wid: d = wid>>2 (dir), b = wid&3 (h-quad). Block owns 64 hidden
// units. 512 threads = 8 waves: gate g=w>>1, k-half c=w&1. Each thread holds
// 128 whh weights (row g*256+b*64+L, cols c*128..+128).
//
// VGPR HISTORY (why 512 threads): 1024-thread blocks cap per-thread VGPRs at
// 128 and the 128 resident weights spill; 8 waves + amdgpu_waves_per_eu(2,2)
// gives a 256-reg budget, residency is cheapest.
// ---------------------------------------------------------------------------
__global__ __launch_bounds__(512)
__attribute__((amdgpu_waves_per_eu(2, 2)))
void lstm_pass(
    const float* __restrict__ xg,   // (2, T, 1024) for this layer
    const float* __restrict__ whh,  // (2, 1024, 256) for this layer
    float* __restrict__ xout,       // (T, 512) concat [hf, hb]
    unsigned long long* __restrict__ pairs, // (2 dirs, 2 slots, 256)
    unsigned long long* __restrict__ rdv)   // 72 slots: [0..63] reports, [64..65] decision
{
    const int tid = threadIdx.x;

    __shared__ __align__(16) float stage[2][256];
    __shared__ float parts[8][64];
    __shared__ int sh_dec[2];

    // ---------------- XCD rendezvous (leader-decided) ----------------
    {
        unsigned xcc;
        asm volatile("s_getreg_b32 %0, hwreg(20, 0, 32)" : "=s"(xcc)); // HW_REG_XCC_ID
        xcc &= 0xfu;
        if (tid == 0)
            __hip_atomic_store(rdv + blockIdx.x,
                               (1ull << 32) | (unsigned long long)xcc,
                               __ATOMIC_RELAXED, __HIP_MEMORY_SCOPE_AGENT);

        // Leader: block 0, wave 0 collects all 64 reports (BOUNDED) and
        // publishes the decision. mask==0 means "use the fallback path".
        if (blockIdx.x == 0 && tid < 64) {
            unsigned long long r = 0;
            bool got = false;
            for (int it = 0; it < 32768; ++it) {
                r = __hip_atomic_load(rdv + tid, __ATOMIC_RELAXED,
                                      __HIP_MEMORY_SCOPE_AGENT);
                if (__all((unsigned)(r >> 32) == 1u)) { got = true; break; }
            }
            unsigned long long mask = 0ull;
            if (got) {
                const unsigned x_i = (unsigned)r & 0xfu;
                const unsigned target =
                    (unsigned)__builtin_amdgcn_readfirstlane((int)x_i) & 0xfu;
                // strict validation: exactly 8 XCDs x 8 blocks each.
                // Anything else (incl. bogus hwreg read) -> fallback.
                bool valid = true;
                unsigned long long mm = 0ull;
                for (unsigned x = 0; x < 8; x++) {
                    unsigned long long m = __ballot(x_i == x);
                    if (__popcll(m) != 8) valid = false;
                    if (x == target) mm = m;
                }
                if (valid) mask = mm;
            }
            if (tid == 0) {
                __hip_atomic_store(rdv + 64, (2ull << 32) | (mask & 0xffffffffull),
                                   __ATOMIC_RELAXED, __HIP_MEMORY_SCOPE_AGENT);
                __hip_atomic_store(rdv + 65, (2ull << 32) | (mask >> 32),
                                   __ATOMIC_RELAXED, __HIP_MEMORY_SCOPE_AGENT);
            }
        }

        // Everyone: wait for the decision (live: leader always publishes).
        if (tid == 0) {
            unsigned long long lo, hi;
            do {
                lo = __hip_atomic_load(rdv + 64, __ATOMIC_RELAXED,
                                       __HIP_MEMORY_SCOPE_AGENT);
            } while ((unsigned)(lo >> 32) != 2u);
            do {
                hi = __hip_atomic_load(rdv + 65, __ATOMIC_RELAXED,
                                       __HIP_MEMORY_SCOPE_AGENT);
            } while ((unsigned)(hi >> 32) != 2u);
            const unsigned long long mask =
                (lo & 0xffffffffull) | ((hi & 0xffffffffull) << 32);
            const int bid = (int)blockIdx.x;
            int fs, wd;
            if (mask != 0ull) {
                fs = 1;
                if ((mask >> bid) & 1ull)
                    wd = __popcll(mask & ((1ull << bid) - 1ull));
                else wd = -1;
            } else {
                fs = 0;
                wd = (bid < 8) ? bid : -1;   // original (round-0) behavior
            }
            sh_dec[0] = fs;
            sh_dec[1] = wd;
        }
        __syncthreads();
    }
    const int fast = sh_dec[0];
    const int wid  = sh_dec[1];
    if (wid < 0) return;   // non-worker blocks free their CU

    const int w = tid >> 6, L = tid & 63;
    const int d = wid >> 2, b = wid & 3;
    const int g = w >> 1, c = w & 1;

    // weight preload: row = g*256 + b*64 + L, cols [c*128, c*128+128)
    float wr[128];
    {
        const float* wp = whh + ((size_t)d << 18) +
                          (size_t)(g * 256 + b * 64 + L) * 256 + c * 128;
#pragma unroll
        for (int i = 0; i < 32; i++) {
            float4 v = ((const float4*)wp)[i];
            wr[4*i+0] = v.x; wr[4*i+1] = v.y; wr[4*i+2] = v.z; wr[4*i+3] = v.w;
        }
    }
    // Defensive: forbid invariant-load remat of the weights.
#pragma unroll
    for (int i = 0; i < 128; i++)
        asm volatile("" : "+v"(wr[i]));

    unsigned long long* mypairs = pairs + (size_t)d * 512;
    const float* xgd = xg + ((size_t)d << 21);

    float cst = 0.f;
    float xgp[4] = {0.f, 0.f, 0.f, 0.f};
    if (w == 7) {
        stage[1][b*64 + L] = 0.f;   // h(0) own chunk for step 1
        int t0 = (d == 0) ? 0 : (T_LEN - 1);
#pragma unroll
        for (int g2 = 0; g2 < 4; g2++)
            xgp[g2] = xgd[((size_t)t0 << 10) + g2*256 + b*64 + L];
    }
    const int pc = (w < 3) ? (w + (w >= b)) : 0;  // probe chunk (remote)

    int use_fast = fast;     // per-wave sticky; only meaningful for w<3
    int budget   = 16384;    // cumulative fast-poll budget (safety net)

    for (int s = 1; s <= T_LEN; s++) {
        const int par = s & 1;
        if (w < 3) {
            unsigned long long* pp = mypairs + ((s-1) & 1) * 256 + pc*64 + L;
            const unsigned tagexp = (unsigned)(s - 1);
            unsigned long long v = 0;
            if (use_fast) {
                for (;;) {
                    asm volatile(
                        "global_load_dwordx2 %0, %1, off sc0\n\t"
                        "s_waitcnt vmcnt(0)"
                        : "=&v"(v) : "v"((unsigned long long)pp) : "memory");
                    if (__all((unsigned)(v >> 32) == tagexp)) break;
                    if (--budget < 0) { use_fast = 0; break; }
                }
            }
            if (!use_fast) {
                for (;;) {
                    v = __hip_atomic_load(pp, __ATOMIC_RELAXED,
                                          __HIP_MEMORY_SCOPE_AGENT);
                    if (__all((unsigned)(v >> 32) == tagexp)) break;
                }
            }
            stage[par][pc*64 + L] = __uint_as_float((unsigned)v);
        }
        __syncthreads();  // h(s-1) complete in stage[par]

        const float4* hv = (const float4*)&stage[par][c*128];
        float acc[4] = {0.f, 0.f, 0.f, 0.f};
#pragma unroll
        for (int k4 = 0; k4 < 32; k4++) {
            float4 h4 = hv[k4];
            acc[k4 & 3] = fmaf(h4.x, wr[4*k4+0], acc[k4 & 3]);
            acc[k4 & 3] = fmaf(h4.y, wr[4*k4+1], acc[k4 & 3]);
            acc[k4 & 3] = fmaf(h4.z, wr[4*k4+2], acc[k4 & 3]);
            acc[k4 & 3] = fmaf(h4.w, wr[4*k4+3], acc[k4 & 3]);
        }
        parts[w][L] = (acc[0] + acc[1]) + (acc[2] + acc[3]);
        __syncthreads();

        if (w == 7) {
            float G[4];
#pragma unroll
            for (int g2 = 0; g2 < 4; g2++)
                G[g2] = parts[2*g2][L] + parts[2*g2+1][L] + xgp[g2];
            float ig = 1.f / (1.f + __expf(-G[0]));
            float fg = 1.f / (1.f + __expf(-G[1]));
            float e2 = __expf(2.f * G[2]);
            float tg = (e2 - 1.f) / (e2 + 1.f);
            float og = 1.f / (1.f + __expf(-G[3]));
            cst = fg * cst + ig * tg;
            float ec = __expf(2.f * cst);
            float th = (ec - 1.f) / (ec + 1.f);
            float h = og * th;
            // publish ASAP (remote blocks are waiting on this)
            const unsigned long long pv =
                ((unsigned long long)(unsigned)s << 32) |
                (unsigned long long)__float_as_uint(h);
            unsigned long long* pa = mypairs + par*256 + b*64 + L;
            if (fast) {
                // L2-visible write-through for co-located pollers ...
                asm volatile("global_store_dwordx2 %0, %1, off sc0"
                             :: "v"((unsigned long long)pa), "v"(pv) : "memory");
                // ... plus the agent store so the IF path stays valid too.
                __hip_atomic_store(pa, pv, __ATOMIC_RELAXED,
                                   __HIP_MEMORY_SCOPE_AGENT);
            } else {
                __hip_atomic_store(pa, pv, __ATOMIC_RELAXED,
                                   __HIP_MEMORY_SCOPE_AGENT);
            }
            stage[1 - par][b*64 + L] = h;   // own chunk for step s+1
            int t = (d == 0) ? (s - 1) : (T_LEN - s);
            xout[(size_t)t * 512 + d*256 + b*64 + L] = h;
            int tn = (d == 0) ? ((s < T_LEN) ? s : (T_LEN - 1))
                              : ((s < T_LEN) ? (T_LEN - 1 - s) : 0);
#pragma unroll
            for (int g2 = 0; g2 < 4; g2++)
                xgp[g2] = xgd[((size_t)tn << 10) + g2*256 + b*64 + L];
        }
    }
}

// ---------------------------------------------------------------------------
// feats[t][n] = dot(x2[t], Wout[n]) + bout[n]
// ---------------------------------------------------------------------------
__global__ __launch_bounds__(64) void feats_kern(
    const float* __restrict__ x2, const float* __restrict__ Wout,
    const float* __restrict__ bout, float* __restrict__ feats)
{
    const int t = blockIdx.x;
    __shared__ __align__(16) float xr[512];
    for (int i = threadIdx.x; i < 128; i += 64)
        ((float4*)xr)[i] = ((const float4*)(x2 + (size_t)t * 512))[i];
    __syncthreads();
    const int n = threadIdx.x;
    if (n < K_TAG) {
        const float4* wrow = (const float4*)(Wout + (size_t)n * 512);
        float acc = 0.f;
#pragma unroll 8
        for (int k4 = 0; k4 < 128; k4++) {
            float4 wv = wrow[k4];
            float4 xv = ((const float4*)xr)[k4];
            acc = fmaf(wv.x, xv.x, acc); acc = fmaf(wv.y, xv.y, acc);
            acc = fmaf(wv.z, xv.z, acc); acc = fmaf(wv.w, xv.w, acc);
        }
        feats[t * K_TAG + n] = acc + bout[n];
    }
}

// ---------------------------------------------------------------------------
// Viterbi: single wave. lane n holds fv[n]; trans[n][p] in VGPRs.
// ---------------------------------------------------------------------------
__global__ __launch_bounds__(64) void viterbi_kern(
    const float* __restrict__ feats, const float* __restrict__ trans,
    unsigned char* __restrict__ bptr, int* __restrict__ bnd,
    float* __restrict__ out)
{
    const int lane = threadIdx.x;
    const bool act = lane < K_TAG;
    float tr[K_TAG];
#pragma unroll
    for (int p = 0; p < K_TAG; p++)
        tr[p] = act ? trans[lane * K_TAG + p] : -3.0e38f;

    float fv = (lane == START_TAG) ? 0.f : NEG_VAL;
    int orig = lane;
    float feat = act ? feats[lane] : 0.f;

    for (int t = 0; t < T_LEN; t++) {
        float featn = (act && (t + 1 < T_LEN)) ? feats[(t + 1) * K_TAG + lane] : 0.f;
        float m = -3.0e38f; int bp = 0;
#pragma unroll
        for (int p = 0; p < K_TAG; p++) {
            float sp = __uint_as_float(__builtin_amdgcn_readlane(__float_as_uint(fv), p));
            float sc = sp + tr[p];
            if (sc > m) { m = sc; bp = p; }
        }
        fv = m + feat;
        feat = featn;
        if (act) bptr[t * K_TAG + lane] = (unsigned char)bp;
        orig = __shfl(orig, bp);
        if ((t & 127) == 127) {
            if (act) bnd[(t >> 7) * K_TAG + lane] = orig;
            orig = lane;
        }
    }
    float term = fv + (act ? trans[END_TAG * K_TAG + lane] : -3.0e38f);
    float bm = -3.0e38f; int bl = 0;
#pragma unroll
    for (int p = 0; p < K_TAG; p++) {
        float v = __uint_as_float(__builtin_amdgcn_readlane(__float_as_uint(term), p));
        if (v > bm) { bm = v; bl = p; }
    }
    if (lane == 0) out[0] = bm;

    __shared__ int sb[16];
    if (lane == 0) {
        int s = bl;
        sb[15] = s;
        for (int k = 15; k >= 1; k--) { s = bnd[k * K_TAG + s]; sb[k - 1] = s; }
    }
    __syncthreads();
    if (lane < 16) {
        int s = sb[lane];
        for (int t = lane * 128 + 127; t >= lane * 128; t--) {
            out[1 + t] = (float)s;
            s = (int)bptr[t * K_TAG + s];
        }
    }
}

// ---------------------------------------------------------------------------
extern "C" void kernel_launch(void* const* d_in, const int* in_sizes, int n_in,
                              void* d_out, int out_size, void* d_ws, size_t ws_size,
                              hipStream_t stream) {
    const int*   sent = (const int*)d_in[0];
    const float* emb  = (const float*)d_in[1];
    const float* wih  = (const float*)d_in[2];   // (2,2,1024,512)
    const float* whh  = (const float*)d_in[3];   // (2,2,1024,256)
    const float* bih  = (const float*)d_in[4];   // (2,2,1024)
    const float* bhh  = (const float*)d_in[5];
    const float* Wout = (const float*)d_in[6];   // (48,512)
    const float* bout = (const float*)d_in[7];   // (48,)
    const float* trans= (const float*)d_in[8];   // (48,48)
    float* out = (float*)d_out;

    float* ws = (float*)d_ws;
    float* xg    = ws;                       // 2*2048*1024 = 4194304 floats
    float* x1    = xg + 4194304;             // 2048*512
    float* x2    = x1 + 1048576;             // 2048*512
    float* feats = x2 + 1048576;             // 2048*48 = 98304
    unsigned long long* pairs = (unsigned long long*)(feats + 98304); // 2 layers * 1024
    unsigned char* bptr = (unsigned char*)(pairs + 2048);             // 2048*48 bytes
    int* bnd = (int*)(bptr + T_LEN * K_TAG);                          // 16*48 ints
    // rdv (2 layers x 72 slots = 1152 B) OVERLAYS the head of bptr: bptr is
    // written only by viterbi_kern, which runs after both lstm passes, so
    // there is no lifetime overlap — keeps total ws footprint identical to
    // the verified round-0 layout.
    unsigned long long* rdv = (unsigned long long*)bptr;

    // zero sync tags + rendezvous slots (ws is poisoned 0xAA before every
    // timed launch). pairs and rdv are contiguous: one memset covers both.
    hipMemsetAsync(pairs, 0, (2048 + 144) * sizeof(unsigned long long), stream);

    dim3 gg(32, 32);
    // layer 1: xg = gather(emb,sent) @ wih[0,*].T + bias
    gemm_xg<<<gg, 256, 0, stream>>>(emb, sent, wih, bih, bhh, xg, 1);
    lstm_pass<<<64, 512, 0, stream>>>(xg, whh, x1, pairs, rdv);
    // layer 2
    gemm_xg<<<gg, 256, 0, stream>>>(x1, nullptr, wih + (1 << 20),
                                    bih + 2048, bhh + 2048, xg, 0);
    lstm_pass<<<64, 512, 0, stream>>>(xg, whh + (1 << 19), x2, pairs + 1024, rdv + 72);
    // projection + viterbi
    feats_kern<<<T_LEN, 64, 0, stream>>>(x2, Wout, bout, feats);
    viterbi_kern<<<1, 64, 0, stream>>>(feats, trans, bptr, bnd, out);
}

// Round 3
// 13947.395 us; speedup vs baseline: 1.1926x; 1.1926x over previous
//
#include <hip/hip_runtime.h>
#include <hip/hip_bf16.h>

// Problem constants
#define T_LEN 2048
#define E_DIM 512
#define H_DIM 256
#define K_TAG 48
#define START_TAG 46
#define END_TAG 47
#define NEG_VAL -10000.0f

// ---------------------------------------------------------------------------
// GEMM: out[d][t][row] = dot(A[t][0:512], W[d*1024+row][0:512]) + bih[n]+bhh[n]
// ---------------------------------------------------------------------------
__global__ __launch_bounds__(256) void gemm_xg(
    const float* __restrict__ Abase, const int* __restrict__ sent,
    const float* __restrict__ Bw, const float* __restrict__ bih,
    const float* __restrict__ bhh, float* __restrict__ out, int useGather)
{
    __shared__ float As[16][68];
    __shared__ float Bs[16][68];
    const int tx = threadIdx.x & 15, ty = threadIdx.x >> 4;
    const int t0 = blockIdx.y * 64, n0 = blockIdx.x * 64;
    const int r  = threadIdx.x >> 2;        // 0..63
    const int kq = (threadIdx.x & 3) * 4;   // 0,4,8,12
    const float* arow;
    if (useGather) arow = Abase + (size_t)sent[t0 + r] * 512 + kq;
    else           arow = Abase + (size_t)(t0 + r) * 512 + kq;
    const float* brow = Bw + (size_t)(n0 + r) * 512 + kq;

    float acc[4][4];
#pragma unroll
    for (int i = 0; i < 4; i++)
#pragma unroll
        for (int j = 0; j < 4; j++) acc[i][j] = 0.f;

    for (int k0 = 0; k0 < 512; k0 += 16) {
        float4 a4 = *(const float4*)(arow + k0);
        float4 b4 = *(const float4*)(brow + k0);
        __syncthreads();
        As[kq+0][r] = a4.x; As[kq+1][r] = a4.y; As[kq+2][r] = a4.z; As[kq+3][r] = a4.w;
        Bs[kq+0][r] = b4.x; Bs[kq+1][r] = b4.y; Bs[kq+2][r] = b4.z; Bs[kq+3][r] = b4.w;
        __syncthreads();
#pragma unroll
        for (int k = 0; k < 16; k++) {
            float4 av = *(const float4*)&As[k][ty*4];
            float4 bv = *(const float4*)&Bs[k][tx*4];
            acc[0][0] = fmaf(av.x, bv.x, acc[0][0]); acc[0][1] = fmaf(av.x, bv.y, acc[0][1]);
            acc[0][2] = fmaf(av.x, bv.z, acc[0][2]); acc[0][3] = fmaf(av.x, bv.w, acc[0][3]);
            acc[1][0] = fmaf(av.y, bv.x, acc[1][0]); acc[1][1] = fmaf(av.y, bv.y, acc[1][1]);
            acc[1][2] = fmaf(av.y, bv.z, acc[1][2]); acc[1][3] = fmaf(av.y, bv.w, acc[1][3]);
            acc[2][0] = fmaf(av.z, bv.x, acc[2][0]); acc[2][1] = fmaf(av.z, bv.y, acc[2][1]);
            acc[2][2] = fmaf(av.z, bv.z, acc[2][2]); acc[2][3] = fmaf(av.z, bv.w, acc[2][3]);
            acc[3][0] = fmaf(av.w, bv.x, acc[3][0]); acc[3][1] = fmaf(av.w, bv.y, acc[3][1]);
            acc[3][2] = fmaf(av.w, bv.z, acc[3][2]); acc[3][3] = fmaf(av.w, bv.w, acc[3][3]);
        }
    }
#pragma unroll
    for (int i = 0; i < 4; i++) {
        int t = t0 + ty*4 + i;
#pragma unroll
        for (int j = 0; j < 4; j++) {
            int n = n0 + tx*4 + j;
            float b = bih[n] + bhh[n];
            out[((size_t)((n >> 10) * 2048 + t) << 10) + (n & 1023)] = acc[i][j] + b;
        }
    }
}

// ---------------------------------------------------------------------------
// LSTM recurrence. Grid = 8 blocks: d = bx>>2 (dir), b = bx&3 (h-quad).
// Block owns 64 hidden units. 512 threads = 8 waves: gate g=w>>1, k-half c=w&1.
// Each thread holds 128 whh weights (row g*256+b*64+L, cols c*128..+128).
//
// VGPR HISTORY (why 512 threads): 1024-thread blocks cap per-thread VGPRs at
// 128 and the 128 resident weights spill; 8 waves + amdgpu_waves_per_eu(2,2)
// gives a 256-reg budget, residency is cheapest.
//
// Cross-block h exchange: tagged {h,step} 8B relaxed AGENT atomics, 2 slots.
// (Round-2 lesson: do NOT try to route this through the local L2 with sc0 —
// the agent store invalidates the line, every poll misses L2 and re-fetches
// from the coherence point, and the exchange got 2x SLOWER. The IF round trip
// is the floor for cross-CU mailboxes; we only pipeline the polling.)
//
// POLL PIPELINING (this round): 2 relaxed agent loads kept in flight; check
// the older while the newer flies. Same memory semantics as the serial poll,
// halves the poll period, so observation slack after the publish becomes
// visible drops from ~1 period (~900cy worst) to ~half.
// ---------------------------------------------------------------------------
__global__ __launch_bounds__(512)
__attribute__((amdgpu_waves_per_eu(2, 2)))
void lstm_pass(
    const float* __restrict__ xg,   // (2, T, 1024) for this layer
    const float* __restrict__ whh,  // (2, 1024, 256) for this layer
    float* __restrict__ xout,       // (T, 512) concat [hf, hb]
    unsigned long long* __restrict__ pairs) // (2 dirs, 2 slots, 256)
{
    const int tid = threadIdx.x;
    const int w = tid >> 6, L = tid & 63;
    const int d = blockIdx.x >> 2, b = blockIdx.x & 3;
    const int g = w >> 1, c = w & 1;

    __shared__ __align__(16) float stage[2][256];
    __shared__ float parts[8][64];

    // weight preload: row = g*256 + b*64 + L, cols [c*128, c*128+128)
    float wr[128];
    {
        const float* wp = whh + ((size_t)d << 18) +
                          (size_t)(g * 256 + b * 64 + L) * 256 + c * 128;
#pragma unroll
        for (int i = 0; i < 32; i++) {
            float4 v = ((const float4*)wp)[i];
            wr[4*i+0] = v.x; wr[4*i+1] = v.y; wr[4*i+2] = v.z; wr[4*i+3] = v.w;
        }
    }
    // Defensive: forbid invariant-load remat of the weights.
#pragma unroll
    for (int i = 0; i < 128; i++)
        asm volatile("" : "+v"(wr[i]));

    unsigned long long* mypairs = pairs + (size_t)d * 512;
    const float* xgd = xg + ((size_t)d << 21);

    float cst = 0.f;
    float xgp[4] = {0.f, 0.f, 0.f, 0.f};
    if (w == 7) {
        stage[1][b*64 + L] = 0.f;   // h(0) own chunk for step 1
        int t0 = (d == 0) ? 0 : (T_LEN - 1);
#pragma unroll
        for (int g2 = 0; g2 < 4; g2++)
            xgp[g2] = xgd[((size_t)t0 << 10) + g2*256 + b*64 + L];
    }
    const int pc = (w < 3) ? (w + (w >= b)) : 0;  // probe chunk (remote)

    for (int s = 1; s <= T_LEN; s++) {
        const int par = s & 1;
        if (w < 3) {
            unsigned long long* pp = mypairs + ((s-1) & 1) * 256 + pc*64 + L;
            const unsigned tagexp = (unsigned)(s - 1);
            // 2-deep pipelined poll: va is the older sample, vb the newer.
            unsigned long long va = __hip_atomic_load(pp, __ATOMIC_RELAXED,
                                                      __HIP_MEMORY_SCOPE_AGENT);
            unsigned long long v;
            for (;;) {
                unsigned long long vb = __hip_atomic_load(pp, __ATOMIC_RELAXED,
                                                          __HIP_MEMORY_SCOPE_AGENT);
                if (__all((unsigned)(va >> 32) == tagexp)) { v = va; break; }
                va = __hip_atomic_load(pp, __ATOMIC_RELAXED,
                                       __HIP_MEMORY_SCOPE_AGENT);
                if (__all((unsigned)(vb >> 32) == tagexp)) { v = vb; break; }
            }
            stage[par][pc*64 + L] = __uint_as_float((unsigned)v);
        }
        __syncthreads();  // h(s-1) complete in stage[par]

        const float4* hv = (const float4*)&stage[par][c*128];
        float acc[4] = {0.f, 0.f, 0.f, 0.f};
#pragma unroll
        for (int k4 = 0; k4 < 32; k4++) {
            float4 h4 = hv[k4];
            acc[k4 & 3] = fmaf(h4.x, wr[4*k4+0], acc[k4 & 3]);
            acc[k4 & 3] = fmaf(h4.y, wr[4*k4+1], acc[k4 & 3]);
            acc[k4 & 3] = fmaf(h4.z, wr[4*k4+2], acc[k4 & 3]);
            acc[k4 & 3] = fmaf(h4.w, wr[4*k4+3], acc[k4 & 3]);
        }
        parts[w][L] = (acc[0] + acc[1]) + (acc[2] + acc[3]);
        __syncthreads();

        if (w == 7) {
            float G[4];
#pragma unroll
            for (int g2 = 0; g2 < 4; g2++)
                G[g2] = parts[2*g2][L] + parts[2*g2+1][L] + xgp[g2];
            float ig = 1.f / (1.f + __expf(-G[0]));
            float fg = 1.f / (1.f + __expf(-G[1]));
            float e2 = __expf(2.f * G[2]);
            float tg = (e2 - 1.f) / (e2 + 1.f);
            float og = 1.f / (1.f + __expf(-G[3]));
            cst = fg * cst + ig * tg;
            float ec = __expf(2.f * cst);
            float th = (ec - 1.f) / (ec + 1.f);
            float h = og * th;
            // publish ASAP (remote blocks are waiting on this)
            __hip_atomic_store(mypairs + par*256 + b*64 + L,
                ((unsigned long long)(unsigned)s << 32) | (unsigned long long)__float_as_uint(h),
                __ATOMIC_RELAXED, __HIP_MEMORY_SCOPE_AGENT);
            stage[1 - par][b*64 + L] = h;   // own chunk for step s+1
            int t = (d == 0) ? (s - 1) : (T_LEN - s);
            xout[(size_t)t * 512 + d*256 + b*64 + L] = h;
            int tn = (d == 0) ? ((s < T_LEN) ? s : (T_LEN - 1))
                              : ((s < T_LEN) ? (T_LEN - 1 - s) : 0);
#pragma unroll
            for (int g2 = 0; g2 < 4; g2++)
                xgp[g2] = xgd[((size_t)tn << 10) + g2*256 + b*64 + L];
        }
    }
}

// ---------------------------------------------------------------------------
// feats[t][n] = dot(x2[t], Wout[n]) + bout[n]
// ---------------------------------------------------------------------------
__global__ __launch_bounds__(64) void feats_kern(
    const float* __restrict__ x2, const float* __restrict__ Wout,
    const float* __restrict__ bout, float* __restrict__ feats)
{
    const int t = blockIdx.x;
    __shared__ __align__(16) float xr[512];
    for (int i = threadIdx.x; i < 128; i += 64)
        ((float4*)xr)[i] = ((const float4*)(x2 + (size_t)t * 512))[i];
    __syncthreads();
    const int n = threadIdx.x;
    if (n < K_TAG) {
        const float4* wrow = (const float4*)(Wout + (size_t)n * 512);
        float acc = 0.f;
#pragma unroll 8
        for (int k4 = 0; k4 < 128; k4++) {
            float4 wv = wrow[k4];
            float4 xv = ((const float4*)xr)[k4];
            acc = fmaf(wv.x, xv.x, acc); acc = fmaf(wv.y, xv.y, acc);
            acc = fmaf(wv.z, xv.z, acc); acc = fmaf(wv.w, xv.w, acc);
        }
        feats[t * K_TAG + n] = acc + bout[n];
    }
}

// ---------------------------------------------------------------------------
// Viterbi: single wave. lane n holds fv[n]; trans[n][p] in VGPRs.
// Inner argmax rewritten as a TOURNAMENT (index-ordered, strict >): the
// round-0 serial 48-long cmp/cndmask chain was latency-bound (~4cy/dep-op on
// a lone wave); the tournament has the same float adds/compares (bit-exact,
// first-max tie semantics preserved) but a ~26-op dependent chain, so the
// step becomes issue-bound. Single-wave kernel: register pressure from the
// unrolled candidates is irrelevant to occupancy.
// ---------------------------------------------------------------------------
__global__ __launch_bounds__(64) void viterbi_kern(
    const float* __restrict__ feats, const float* __restrict__ trans,
    unsigned char* __restrict__ bptr, int* __restrict__ bnd,
    float* __restrict__ out)
{
    const int lane = threadIdx.x;
    const bool act = lane < K_TAG;
    float tr[K_TAG];
#pragma unroll
    for (int p = 0; p < K_TAG; p++)
        tr[p] = act ? trans[lane * K_TAG + p] : -3.0e38f;

    float fv = (lane == START_TAG) ? 0.f : NEG_VAL;
    int orig = lane;
    float feat = act ? feats[lane] : 0.f;

    for (int t = 0; t < T_LEN; t++) {
        float featn = (act && (t + 1 < T_LEN)) ? feats[(t + 1) * K_TAG + lane] : 0.f;

        // candidates: cand[p] = fv[p] + tr[lane][p]  (same adds as before)
        float cand[K_TAG];
#pragma unroll
        for (int p = 0; p < K_TAG; p++)
            cand[p] = __uint_as_float(__builtin_amdgcn_readlane(__float_as_uint(fv), p))
                      + tr[p];

        // tournament max with first-index tie semantics: adjacent pairing
        // keeps indices ordered; later index wins only on STRICT >.
        float m24[24]; int b24[24];
#pragma unroll
        for (int i = 0; i < 24; i++) {
            bool gsel = cand[2*i+1] > cand[2*i];
            m24[i] = gsel ? cand[2*i+1] : cand[2*i];
            b24[i] = gsel ? (2*i+1) : (2*i);
        }
        float m12[12]; int b12[12];
#pragma unroll
        for (int i = 0; i < 12; i++) {
            bool gsel = m24[2*i+1] > m24[2*i];
            m12[i] = gsel ? m24[2*i+1] : m24[2*i];
            b12[i] = gsel ? b24[2*i+1] : b24[2*i];
        }
        float m6[6]; int b6[6];
#pragma unroll
        for (int i = 0; i < 6; i++) {
            bool gsel = m12[2*i+1] > m12[2*i];
            m6[i] = gsel ? m12[2*i+1] : m12[2*i];
            b6[i] = gsel ? b12[2*i+1] : b12[2*i];
        }
        float m3[3]; int b3[3];
#pragma unroll
        for (int i = 0; i < 3; i++) {
            bool gsel = m6[2*i+1] > m6[2*i];
            m3[i] = gsel ? m6[2*i+1] : m6[2*i];
            b3[i] = gsel ? b6[2*i+1] : b6[2*i];
        }
        float m = m3[0]; int bp = b3[0];
        if (m3[1] > m) { m = m3[1]; bp = b3[1]; }
        if (m3[2] > m) { m = m3[2]; bp = b3[2]; }

        fv = m + feat;
        feat = featn;
        if (act) bptr[t * K_TAG + lane] = (unsigned char)bp;
        orig = __shfl(orig, bp);
        if ((t & 127) == 127) {
            if (act) bnd[(t >> 7) * K_TAG + lane] = orig;
            orig = lane;
        }
    }
    float term = fv + (act ? trans[END_TAG * K_TAG + lane] : -3.0e38f);
    float bm = -3.0e38f; int bl = 0;
#pragma unroll
    for (int p = 0; p < K_TAG; p++) {
        float v = __uint_as_float(__builtin_amdgcn_readlane(__float_as_uint(term), p));
        if (v > bm) { bm = v; bl = p; }
    }
    if (lane == 0) out[0] = bm;

    __shared__ int sb[16];
    if (lane == 0) {
        int s = bl;
        sb[15] = s;
        for (int k = 15; k >= 1; k--) { s = bnd[k * K_TAG + s]; sb[k - 1] = s; }
    }
    __syncthreads();
    if (lane < 16) {
        int s = sb[lane];
        for (int t = lane * 128 + 127; t >= lane * 128; t--) {
            out[1 + t] = (float)s;
            s = (int)bptr[t * K_TAG + s];
        }
    }
}

// ---------------------------------------------------------------------------
extern "C" void kernel_launch(void* const* d_in, const int* in_sizes, int n_in,
                              void* d_out, int out_size, void* d_ws, size_t ws_size,
                              hipStream_t stream) {
    const int*   sent = (const int*)d_in[0];
    const float* emb  = (const float*)d_in[1];
    const float* wih  = (const float*)d_in[2];   // (2,2,1024,512)
    const float* whh  = (const float*)d_in[3];   // (2,2,1024,256)
    const float* bih  = (const float*)d_in[4];   // (2,2,1024)
    const float* bhh  = (const float*)d_in[5];
    const float* Wout = (const float*)d_in[6];   // (48,512)
    const float* bout = (const float*)d_in[7];   // (48,)
    const float* trans= (const float*)d_in[8];   // (48,48)
    float* out = (float*)d_out;

    float* ws = (float*)d_ws;
    float* xg    = ws;                       // 2*2048*1024 = 4194304 floats
    float* x1    = xg + 4194304;             // 2048*512
    float* x2    = x1 + 1048576;             // 2048*512
    float* feats = x2 + 1048576;             // 2048*48 = 98304
    unsigned long long* pairs = (unsigned long long*)(feats + 98304); // 2 layers * 1024
    unsigned char* bptr = (unsigned char*)(pairs + 2048);             // 2048*48 bytes
    int* bnd = (int*)(bptr + T_LEN * K_TAG);                          // 16*48 ints

    // zero sync tags (ws is poisoned 0xAA before every timed launch)
    hipMemsetAsync(pairs, 0, 2048 * sizeof(unsigned long long), stream);

    dim3 gg(32, 32);
    // layer 1: xg = gather(emb,sent) @ wih[0,*].T + bias
    gemm_xg<<<gg, 256, 0, stream>>>(emb, sent, wih, bih, bhh, xg, 1);
    lstm_pass<<<8, 512, 0, stream>>>(xg, whh, x1, pairs);
    // layer 2
    gemm_xg<<<gg, 256, 0, stream>>>(x1, nullptr, wih + (1 << 20),
                                    bih + 2048, bhh + 2048, xg, 0);
    lstm_pass<<<8, 512, 0, stream>>>(xg, whh + (1 << 19), x2, pairs + 1024);
    // projection + viterbi
    feats_kern<<<T_LEN, 64, 0, stream>>>(x2, Wout, bout, feats);
    viterbi_kern<<<1, 64, 0, stream>>>(feats, trans, bptr, bnd, out);
}

// Round 4
// 9525.060 us; speedup vs baseline: 1.7463x; 1.4643x over previous
//
#include <hip/hip_runtime.h>
#include <hip/hip_bf16.h>

// Problem constants
#define T_LEN 2048
#define E_DIM 512
#define H_DIM 256
#define K_TAG 48
#define START_TAG 46
#define END_TAG 47
#define NEG_VAL -10000.0f

// ---------------------------------------------------------------------------
// GEMM: out[d][t][row] = dot(A[t][0:512], W[d*1024+row][0:512]) + bih[n]+bhh[n]
// ---------------------------------------------------------------------------
__global__ __launch_bounds__(256) void gemm_xg(
    const float* __restrict__ Abase, const int* __restrict__ sent,
    const float* __restrict__ Bw, const float* __restrict__ bih,
    const float* __restrict__ bhh, float* __restrict__ out, int useGather)
{
    __shared__ float As[16][68];
    __shared__ float Bs[16][68];
    const int tx = threadIdx.x & 15, ty = threadIdx.x >> 4;
    const int t0 = blockIdx.y * 64, n0 = blockIdx.x * 64;
    const int r  = threadIdx.x >> 2;        // 0..63
    const int kq = (threadIdx.x & 3) * 4;   // 0,4,8,12
    const float* arow;
    if (useGather) arow = Abase + (size_t)sent[t0 + r] * 512 + kq;
    else           arow = Abase + (size_t)(t0 + r) * 512 + kq;
    const float* brow = Bw + (size_t)(n0 + r) * 512 + kq;

    float acc[4][4];
#pragma unroll
    for (int i = 0; i < 4; i++)
#pragma unroll
        for (int j = 0; j < 4; j++) acc[i][j] = 0.f;

    for (int k0 = 0; k0 < 512; k0 += 16) {
        float4 a4 = *(const float4*)(arow + k0);
        float4 b4 = *(const float4*)(brow + k0);
        __syncthreads();
        As[kq+0][r] = a4.x; As[kq+1][r] = a4.y; As[kq+2][r] = a4.z; As[kq+3][r] = a4.w;
        Bs[kq+0][r] = b4.x; Bs[kq+1][r] = b4.y; Bs[kq+2][r] = b4.z; Bs[kq+3][r] = b4.w;
        __syncthreads();
#pragma unroll
        for (int k = 0; k < 16; k++) {
            float4 av = *(const float4*)&As[k][ty*4];
            float4 bv = *(const float4*)&Bs[k][tx*4];
            acc[0][0] = fmaf(av.x, bv.x, acc[0][0]); acc[0][1] = fmaf(av.x, bv.y, acc[0][1]);
            acc[0][2] = fmaf(av.x, bv.z, acc[0][2]); acc[0][3] = fmaf(av.x, bv.w, acc[0][3]);
            acc[1][0] = fmaf(av.y, bv.x, acc[1][0]); acc[1][1] = fmaf(av.y, bv.y, acc[1][1]);
            acc[1][2] = fmaf(av.y, bv.z, acc[1][2]); acc[1][3] = fmaf(av.y, bv.w, acc[1][3]);
            acc[2][0] = fmaf(av.z, bv.x, acc[2][0]); acc[2][1] = fmaf(av.z, bv.y, acc[2][1]);
            acc[2][2] = fmaf(av.z, bv.z, acc[2][2]); acc[2][3] = fmaf(av.z, bv.w, acc[2][3]);
            acc[3][0] = fmaf(av.w, bv.x, acc[3][0]); acc[3][1] = fmaf(av.w, bv.y, acc[3][1]);
            acc[3][2] = fmaf(av.w, bv.z, acc[3][2]); acc[3][3] = fmaf(av.w, bv.w, acc[3][3]);
        }
    }
#pragma unroll
    for (int i = 0; i < 4; i++) {
        int t = t0 + ty*4 + i;
#pragma unroll
        for (int j = 0; j < 4; j++) {
            int n = n0 + tx*4 + j;
            float b = bih[n] + bhh[n];
            out[((size_t)((n >> 10) * 2048 + t) << 10) + (n & 1023)] = acc[i][j] + b;
        }
    }
}

// ---------------------------------------------------------------------------
// LSTM recurrence. Grid = 64 blocks; leader-decided rendezvous (proven safe
// in round 2) picks 8 WORKERS co-located on block-0's XCD. The per-step h
// exchange then travels through that XCD's SHARED L2 (sc0 store / sc0 load,
// ~200cy RT) instead of the Infinity-Fabric round trip (~900+cy) that
// agent-scope atomics pay.
//
// ROUND-2 LESSON (why TWO mailboxes): dual-storing fast+agent to the SAME
// address makes the agent(sc1) store evict the line from the local L2, so
// every "fast" poll was an L2 miss to the coherence point -> 2x SLOWER.
// Fix: fpairs (sc0, stays dirty in local L2) and pairs (agent) are separate
// cache lines; the agent store can no longer kill the fast line.
//
// HANG-SAFETY:
//  * rendezvous: bounded leader collect + unconditional decision publish
//    (round-2 protocol, verbatim). Validation failure -> exact round-0 path.
//  * fast poll: PER-STEP budget (256) with sticky fallback to the agent
//    mailbox, which the publisher ALWAYS feeds. A broken fast path costs a
//    one-time ~27us, never a hang. (Per-step, not cumulative: a healthy
//    fast path legitimately burns a few polls every step.)
//
// Worker wid: d = wid>>2 (dir), b = wid&3 (h-quad). Block owns 64 hidden
// units. 512 threads = 8 waves: gate g=w>>1, k-half c=w&1. Each thread holds
// 128 whh weights (row g*256+b*64+L, cols c*128..+128).
// VGPR HISTORY (why 512 threads): 1024-thread blocks cap per-thread VGPRs at
// 128 and the 128 resident weights spill; 8 waves + amdgpu_waves_per_eu(2,2)
// gives a 256-reg budget, residency is cheapest.
// ---------------------------------------------------------------------------
__global__ __launch_bounds__(512)
__attribute__((amdgpu_waves_per_eu(2, 2)))
void lstm_pass(
    const float* __restrict__ xg,   // (2, T, 1024) for this layer
    const float* __restrict__ whh,  // (2, 1024, 256) for this layer
    float* __restrict__ xout,       // (T, 512) concat [hf, hb]
    unsigned long long* __restrict__ pairs,  // agent mailbox (2 dirs, 2 slots, 256)
    unsigned long long* __restrict__ fpairs, // fast (L2) mailbox, same layout
    unsigned long long* __restrict__ rdv)    // 72 slots: [0..63] reports, [64..65] decision
{
    const int tid = threadIdx.x;

    __shared__ __align__(16) float stage[2][256];
    __shared__ float parts[8][64];
    __shared__ int sh_dec[2];

    // ---------------- XCD rendezvous (leader-decided; round-2 proven) ------
    {
        unsigned xcc;
        asm volatile("s_getreg_b32 %0, hwreg(20, 0, 32)" : "=s"(xcc)); // HW_REG_XCC_ID
        xcc &= 0xfu;
        if (tid == 0)
            __hip_atomic_store(rdv + blockIdx.x,
                               (1ull << 32) | (unsigned long long)xcc,
                               __ATOMIC_RELAXED, __HIP_MEMORY_SCOPE_AGENT);

        if (blockIdx.x == 0 && tid < 64) {
            unsigned long long r = 0;
            bool got = false;
            for (int it = 0; it < 32768; ++it) {
                r = __hip_atomic_load(rdv + tid, __ATOMIC_RELAXED,
                                      __HIP_MEMORY_SCOPE_AGENT);
                if (__all((unsigned)(r >> 32) == 1u)) { got = true; break; }
            }
            unsigned long long mask = 0ull;
            if (got) {
                const unsigned x_i = (unsigned)r & 0xfu;
                const unsigned target =
                    (unsigned)__builtin_amdgcn_readfirstlane((int)x_i) & 0xfu;
                bool valid = true;
                unsigned long long mm = 0ull;
                for (unsigned x = 0; x < 8; x++) {
                    unsigned long long m = __ballot(x_i == x);
                    if (__popcll(m) != 8) valid = false;
                    if (x == target) mm = m;
                }
                if (valid) mask = mm;
            }
            if (tid == 0) {
                __hip_atomic_store(rdv + 64, (2ull << 32) | (mask & 0xffffffffull),
                                   __ATOMIC_RELAXED, __HIP_MEMORY_SCOPE_AGENT);
                __hip_atomic_store(rdv + 65, (2ull << 32) | (mask >> 32),
                                   __ATOMIC_RELAXED, __HIP_MEMORY_SCOPE_AGENT);
            }
        }

        if (tid == 0) {
            unsigned long long lo, hi;
            do {
                lo = __hip_atomic_load(rdv + 64, __ATOMIC_RELAXED,
                                       __HIP_MEMORY_SCOPE_AGENT);
            } while ((unsigned)(lo >> 32) != 2u);
            do {
                hi = __hip_atomic_load(rdv + 65, __ATOMIC_RELAXED,
                                       __HIP_MEMORY_SCOPE_AGENT);
            } while ((unsigned)(hi >> 32) != 2u);
            const unsigned long long mask =
                (lo & 0xffffffffull) | ((hi & 0xffffffffull) << 32);
            const int bid = (int)blockIdx.x;
            int fs, wd;
            if (mask != 0ull) {
                fs = 1;
                if ((mask >> bid) & 1ull)
                    wd = __popcll(mask & ((1ull << bid) - 1ull));
                else wd = -1;
            } else {
                fs = 0;
                wd = (bid < 8) ? bid : -1;   // exact round-0 behavior
            }
            sh_dec[0] = fs;
            sh_dec[1] = wd;
        }
        __syncthreads();
    }
    const int fast = sh_dec[0];
    const int wid  = sh_dec[1];
    if (wid < 0) return;   // non-worker blocks free their CU

    const int w = tid >> 6, L = tid & 63;
    const int d = wid >> 2, b = wid & 3;
    const int g = w >> 1, c = w & 1;

    // weight preload: row = g*256 + b*64 + L, cols [c*128, c*128+128)
    float wr[128];
    {
        const float* wp = whh + ((size_t)d << 18) +
                          (size_t)(g * 256 + b * 64 + L) * 256 + c * 128;
#pragma unroll
        for (int i = 0; i < 32; i++) {
            float4 v = ((const float4*)wp)[i];
            wr[4*i+0] = v.x; wr[4*i+1] = v.y; wr[4*i+2] = v.z; wr[4*i+3] = v.w;
        }
    }
    // Defensive: forbid invariant-load remat of the weights.
#pragma unroll
    for (int i = 0; i < 128; i++)
        asm volatile("" : "+v"(wr[i]));

    unsigned long long* mypairs = pairs  + (size_t)d * 512;
    unsigned long long* myfast  = fpairs + (size_t)d * 512;
    const float* xgd = xg + ((size_t)d << 21);

    float cst = 0.f;
    float xgp[4] = {0.f, 0.f, 0.f, 0.f};
    if (w == 7) {
        stage[1][b*64 + L] = 0.f;   // h(0) own chunk for step 1
        int t0 = (d == 0) ? 0 : (T_LEN - 1);
#pragma unroll
        for (int g2 = 0; g2 < 4; g2++)
            xgp[g2] = xgd[((size_t)t0 << 10) + g2*256 + b*64 + L];
    }
    const int pc = (w < 3) ? (w + (w >= b)) : 0;  // probe chunk (remote)

    int healthy = fast;   // sticky per-wave; meaningful only for w<3

    for (int s = 1; s <= T_LEN; s++) {
        const int par = s & 1;
        if (w < 3) {
            const int off = ((s-1) & 1) * 256 + pc*64 + L;
            const unsigned tagexp = (unsigned)(s - 1);
            unsigned long long v = 0;
            if (healthy) {
                unsigned long long* ppf = myfast + off;
                int bq = 256;   // per-step budget
                for (;;) {
                    asm volatile(
                        "global_load_dwordx2 %0, %1, off sc0\n\t"
                        "s_waitcnt vmcnt(0)"
                        : "=&v"(v) : "v"((unsigned long long)ppf) : "memory");
                    if (__all((unsigned)(v >> 32) == tagexp)) break;
                    if (--bq == 0) { healthy = 0; break; }
                }
            }
            if (!healthy) {
                unsigned long long* pp = mypairs + off;
                for (;;) {
                    v = __hip_atomic_load(pp, __ATOMIC_RELAXED,
                                          __HIP_MEMORY_SCOPE_AGENT);
                    if (__all((unsigned)(v >> 32) == tagexp)) break;
                }
            }
            stage[par][pc*64 + L] = __uint_as_float((unsigned)v);
        }
        __syncthreads();  // h(s-1) complete in stage[par]

        const float4* hv = (const float4*)&stage[par][c*128];
        float acc[4] = {0.f, 0.f, 0.f, 0.f};
#pragma unroll
        for (int k4 = 0; k4 < 32; k4++) {
            float4 h4 = hv[k4];
            acc[k4 & 3] = fmaf(h4.x, wr[4*k4+0], acc[k4 & 3]);
            acc[k4 & 3] = fmaf(h4.y, wr[4*k4+1], acc[k4 & 3]);
            acc[k4 & 3] = fmaf(h4.z, wr[4*k4+2], acc[k4 & 3]);
            acc[k4 & 3] = fmaf(h4.w, wr[4*k4+3], acc[k4 & 3]);
        }
        parts[w][L] = (acc[0] + acc[1]) + (acc[2] + acc[3]);
        __syncthreads();

        if (w == 7) {
            float G[4];
#pragma unroll
            for (int g2 = 0; g2 < 4; g2++)
                G[g2] = parts[2*g2][L] + parts[2*g2+1][L] + xgp[g2];
            float ig = 1.f / (1.f + __expf(-G[0]));
            float fg = 1.f / (1.f + __expf(-G[1]));
            float e2 = __expf(2.f * G[2]);
            float tg = (e2 - 1.f) / (e2 + 1.f);
            float og = 1.f / (1.f + __expf(-G[3]));
            cst = fg * cst + ig * tg;
            float ec = __expf(2.f * cst);
            float th = (ec - 1.f) / (ec + 1.f);
            float h = og * th;
            // publish ASAP (remote blocks are waiting on this)
            const unsigned long long pv =
                ((unsigned long long)(unsigned)s << 32) |
                (unsigned long long)__float_as_uint(h);
            const int poff = par*256 + b*64 + L;
            if (fast) {
                // fast line first (co-located pollers), separate cache line
                asm volatile("global_store_dwordx2 %0, %1, off sc0"
                             :: "v"((unsigned long long)(myfast + poff)),
                                "v"(pv) : "memory");
            }
            // agent mailbox always fed (fallback validity)
            __hip_atomic_store(mypairs + poff, pv,
                               __ATOMIC_RELAXED, __HIP_MEMORY_SCOPE_AGENT);
            stage[1 - par][b*64 + L] = h;   // own chunk for step s+1
            int t = (d == 0) ? (s - 1) : (T_LEN - s);
            xout[(size_t)t * 512 + d*256 + b*64 + L] = h;
            int tn = (d == 0) ? ((s < T_LEN) ? s : (T_LEN - 1))
                              : ((s < T_LEN) ? (T_LEN - 1 - s) : 0);
#pragma unroll
            for (int g2 = 0; g2 < 4; g2++)
                xgp[g2] = xgd[((size_t)tn << 10) + g2*256 + b*64 + L];
        }
    }
}

// ---------------------------------------------------------------------------
// feats[t][n] = dot(x2[t], Wout[n]) + bout[n]
// ---------------------------------------------------------------------------
__global__ __launch_bounds__(64) void feats_kern(
    const float* __restrict__ x2, const float* __restrict__ Wout,
    const float* __restrict__ bout, float* __restrict__ feats)
{
    const int t = blockIdx.x;
    __shared__ __align__(16) float xr[512];
    for (int i = threadIdx.x; i < 128; i += 64)
        ((float4*)xr)[i] = ((const float4*)(x2 + (size_t)t * 512))[i];
    __syncthreads();
    const int n = threadIdx.x;
    if (n < K_TAG) {
        const float4* wrow = (const float4*)(Wout + (size_t)n * 512);
        float acc = 0.f;
#pragma unroll 8
        for (int k4 = 0; k4 < 128; k4++) {
            float4 wv = wrow[k4];
            float4 xv = ((const float4*)xr)[k4];
            acc = fmaf(wv.x, xv.x, acc); acc = fmaf(wv.y, xv.y, acc);
            acc = fmaf(wv.z, xv.z, acc); acc = fmaf(wv.w, xv.w, acc);
        }
        feats[t * K_TAG + n] = acc + bout[n];
    }
}

// ---------------------------------------------------------------------------
// Viterbi: single wave. lane n holds fv[n]; trans[n][p] in VGPRs.
// ROUND-3 LESSON: the full 48-wide tournament kept ~140 values live and the
// default-occupancy VGPR budget (64 regs) spilled them to scratch -> 2.7x
// SLOWER. This version: (a) amdgpu_waves_per_eu(1,1) raises the budget to
// 512 regs (single-wave kernel, occupancy irrelevant), (b) grouped-8
// tournament keeps the live set ~80. Dep chain per step: ~7 dependent
// selects per group (6 groups run interleaved) + 5 final selects, vs 48
// serial selects in round-0. Same float adds/compares, ascending order +
// strict > preserves first-max tie semantics exactly (bit-identical).
// ---------------------------------------------------------------------------
__global__ __launch_bounds__(64)
__attribute__((amdgpu_waves_per_eu(1, 1)))
void viterbi_kern(
    const float* __restrict__ feats, const float* __restrict__ trans,
    unsigned char* __restrict__ bptr, int* __restrict__ bnd,
    float* __restrict__ out)
{
    const int lane = threadIdx.x;
    const bool act = lane < K_TAG;
    float tr[K_TAG];
#pragma unroll
    for (int p = 0; p < K_TAG; p++)
        tr[p] = act ? trans[lane * K_TAG + p] : -3.0e38f;

    float fv = (lane == START_TAG) ? 0.f : NEG_VAL;
    int orig = lane;
    float feat = act ? feats[lane] : 0.f;

    for (int t = 0; t < T_LEN; t++) {
        float featn = (act && (t + 1 < T_LEN)) ? feats[(t + 1) * K_TAG + lane] : 0.f;

        // 6 groups of 8, each reduced serially (ascending, strict > keeps
        // first max); groups are independent -> chains interleave.
        float gm[6]; int gb[6];
#pragma unroll
        for (int q = 0; q < 6; q++) {
            float m = __uint_as_float(
                __builtin_amdgcn_readlane(__float_as_uint(fv), 8*q)) + tr[8*q];
            int bp = 8*q;
#pragma unroll
            for (int j = 1; j < 8; j++) {
                float sc = __uint_as_float(
                    __builtin_amdgcn_readlane(__float_as_uint(fv), 8*q+j)) + tr[8*q+j];
                if (sc > m) { m = sc; bp = 8*q + j; }
            }
            gm[q] = m; gb[q] = bp;
        }
        float m = gm[0]; int bp = gb[0];
#pragma unroll
        for (int q = 1; q < 6; q++)
            if (gm[q] > m) { m = gm[q]; bp = gb[q]; }

        fv = m + feat;
        feat = featn;
        if (act) bptr[t * K_TAG + lane] = (unsigned char)bp;
        orig = __shfl(orig, bp);
        if ((t & 127) == 127) {
            if (act) bnd[(t >> 7) * K_TAG + lane] = orig;
            orig = lane;
        }
    }
    float term = fv + (act ? trans[END_TAG * K_TAG + lane] : -3.0e38f);
    float bm = -3.0e38f; int bl = 0;
#pragma unroll
    for (int p = 0; p < K_TAG; p++) {
        float v = __uint_as_float(__builtin_amdgcn_readlane(__float_as_uint(term), p));
        if (v > bm) { bm = v; bl = p; }
    }
    if (lane == 0) out[0] = bm;

    __shared__ int sb[16];
    if (lane == 0) {
        int s = bl;
        sb[15] = s;
        for (int k = 15; k >= 1; k--) { s = bnd[k * K_TAG + s]; sb[k - 1] = s; }
    }
    __syncthreads();
    if (lane < 16) {
        int s = sb[lane];
        for (int t = lane * 128 + 127; t >= lane * 128; t--) {
            out[1 + t] = (float)s;
            s = (int)bptr[t * K_TAG + s];
        }
    }
}

// ---------------------------------------------------------------------------
extern "C" void kernel_launch(void* const* d_in, const int* in_sizes, int n_in,
                              void* d_out, int out_size, void* d_ws, size_t ws_size,
                              hipStream_t stream) {
    const int*   sent = (const int*)d_in[0];
    const float* emb  = (const float*)d_in[1];
    const float* wih  = (const float*)d_in[2];   // (2,2,1024,512)
    const float* whh  = (const float*)d_in[3];   // (2,2,1024,256)
    const float* bih  = (const float*)d_in[4];   // (2,2,1024)
    const float* bhh  = (const float*)d_in[5];
    const float* Wout = (const float*)d_in[6];   // (48,512)
    const float* bout = (const float*)d_in[7];   // (48,)
    const float* trans= (const float*)d_in[8];   // (48,48)
    float* out = (float*)d_out;

    float* ws = (float*)d_ws;
    float* xg    = ws;                       // 2*2048*1024 = 4194304 floats
    float* x1    = xg + 4194304;             // 2048*512
    float* x2    = x1 + 1048576;             // 2048*512
    float* feats = x2 + 1048576;             // 2048*48 = 98304
    unsigned long long* pairs = (unsigned long long*)(feats + 98304); // 2 layers * 1024
    unsigned char* bptr = (unsigned char*)(pairs + 2048);             // 2048*48 bytes
    int* bnd = (int*)(bptr + T_LEN * K_TAG);                          // 16*48 ints
    // rdv (2 layers x 72 slots) and fpairs (2 layers x 1024 slots) OVERLAY
    // the head of bptr: bptr is written only by viterbi_kern, which runs
    // after both lstm passes — no lifetime overlap, zero ws growth (the
    // round-2-proven trick).
    unsigned long long* rdv    = (unsigned long long*)bptr;           // 144 slots
    unsigned long long* fpairs = (unsigned long long*)bptr + 256;     // 2048 slots

    // zero sync tags + rendezvous + fast mailbox (ws is poisoned 0xAA before
    // every timed launch)
    hipMemsetAsync(pairs, 0, 2048 * sizeof(unsigned long long), stream);
    hipMemsetAsync(bptr,  0, 2304 * sizeof(unsigned long long), stream);

    dim3 gg(32, 32);
    // layer 1: xg = gather(emb,sent) @ wih[0,*].T + bias
    gemm_xg<<<gg, 256, 0, stream>>>(emb, sent, wih, bih, bhh, xg, 1);
    lstm_pass<<<64, 512, 0, stream>>>(xg, whh, x1, pairs, fpairs, rdv);
    // layer 2
    gemm_xg<<<gg, 256, 0, stream>>>(x1, nullptr, wih + (1 << 20),
                                    bih + 2048, bhh + 2048, xg, 0);
    lstm_pass<<<64, 512, 0, stream>>>(xg, whh + (1 << 19), x2,
                                      pairs + 1024, fpairs + 1024, rdv + 72);
    // projection + viterbi
    feats_kern<<<T_LEN, 64, 0, stream>>>(x2, Wout, bout, feats);
    viterbi_kern<<<1, 64, 0, stream>>>(feats, trans, bptr, bnd, out);
}

// Round 5
// 8785.648 us; speedup vs baseline: 1.8932x; 1.0842x over previous
//
#include <hip/hip_runtime.h>
#include <hip/hip_bf16.h>

// Problem constants
#define T_LEN 2048
#define E_DIM 512
#define H_DIM 256
#define K_TAG 48
#define START_TAG 46
#define END_TAG 47
#define NEG_VAL -10000.0f

// ---------------------------------------------------------------------------
// GEMM: out[d][t][row] = dot(A[t][0:512], W[d*1024+row][0:512]) + bih[n]+bhh[n]
// ---------------------------------------------------------------------------
__global__ __launch_bounds__(256) void gemm_xg(
    const float* __restrict__ Abase, const int* __restrict__ sent,
    const float* __restrict__ Bw, const float* __restrict__ bih,
    const float* __restrict__ bhh, float* __restrict__ out, int useGather)
{
    __shared__ float As[16][68];
    __shared__ float Bs[16][68];
    const int tx = threadIdx.x & 15, ty = threadIdx.x >> 4;
    const int t0 = blockIdx.y * 64, n0 = blockIdx.x * 64;
    const int r  = threadIdx.x >> 2;        // 0..63
    const int kq = (threadIdx.x & 3) * 4;   // 0,4,8,12
    const float* arow;
    if (useGather) arow = Abase + (size_t)sent[t0 + r] * 512 + kq;
    else           arow = Abase + (size_t)(t0 + r) * 512 + kq;
    const float* brow = Bw + (size_t)(n0 + r) * 512 + kq;

    float acc[4][4];
#pragma unroll
    for (int i = 0; i < 4; i++)
#pragma unroll
        for (int j = 0; j < 4; j++) acc[i][j] = 0.f;

    for (int k0 = 0; k0 < 512; k0 += 16) {
        float4 a4 = *(const float4*)(arow + k0);
        float4 b4 = *(const float4*)(brow + k0);
        __syncthreads();
        As[kq+0][r] = a4.x; As[kq+1][r] = a4.y; As[kq+2][r] = a4.z; As[kq+3][r] = a4.w;
        Bs[kq+0][r] = b4.x; Bs[kq+1][r] = b4.y; Bs[kq+2][r] = b4.z; Bs[kq+3][r] = b4.w;
        __syncthreads();
#pragma unroll
        for (int k = 0; k < 16; k++) {
            float4 av = *(const float4*)&As[k][ty*4];
            float4 bv = *(const float4*)&Bs[k][tx*4];
            acc[0][0] = fmaf(av.x, bv.x, acc[0][0]); acc[0][1] = fmaf(av.x, bv.y, acc[0][1]);
            acc[0][2] = fmaf(av.x, bv.z, acc[0][2]); acc[0][3] = fmaf(av.x, bv.w, acc[0][3]);
            acc[1][0] = fmaf(av.y, bv.x, acc[1][0]); acc[1][1] = fmaf(av.y, bv.y, acc[1][1]);
            acc[1][2] = fmaf(av.y, bv.z, acc[1][2]); acc[1][3] = fmaf(av.y, bv.w, acc[1][3]);
            acc[2][0] = fmaf(av.z, bv.x, acc[2][0]); acc[2][1] = fmaf(av.z, bv.y, acc[2][1]);
            acc[2][2] = fmaf(av.z, bv.z, acc[2][2]); acc[2][3] = fmaf(av.z, bv.w, acc[2][3]);
            acc[3][0] = fmaf(av.w, bv.x, acc[3][0]); acc[3][1] = fmaf(av.w, bv.y, acc[3][1]);
            acc[3][2] = fmaf(av.w, bv.z, acc[3][2]); acc[3][3] = fmaf(av.w, bv.w, acc[3][3]);
        }
    }
#pragma unroll
    for (int i = 0; i < 4; i++) {
        int t = t0 + ty*4 + i;
#pragma unroll
        for (int j = 0; j < 4; j++) {
            int n = n0 + tx*4 + j;
            float b = bih[n] + bhh[n];
            out[((size_t)((n >> 10) * 2048 + t) << 10) + (n & 1023)] = acc[i][j] + b;
        }
    }
}

// ---------------------------------------------------------------------------
// LSTM recurrence. Grid = 64 blocks; leader-decided rendezvous (round-2/4
// proven) picks 8 WORKERS co-located on block-0's XCD; h exchange through
// that XCD's shared L2 (sc0 mailbox on its own cache lines, round-4 verified:
// FETCH -5.7MB, WRITE +10KB => polls are L2 hits, lines stay dirty in L2).
//
// ROUND-4 LESSON (the real step cost): the matvec read h from LDS as
// WAVE-UNIFORM ds_read_b128 broadcasts — 8 waves x 32 = 256 LDS instrs/step
// each delivering only 16 useful bytes (~12cy apiece ≈ 3000cy of the 4440cy
// step). THIS round: one ds_read_b64/wave distributes h across lanes
// (2 floats/lane), and the matvec broadcasts via v_readlane (SGPR operand
// into v_fma). LDS ops/step/CU: 256 -> 8. Accumulation order is replicated
// EXACTLY (same acc[k4&3] grouping, same in-chain order) => bit-identical.
// Also: w7's xgp prefetch is double-buffered and issued right after
// barrier-1 so the matvec covers its latency before the vmcnt-drain at
// barrier-2 (previously it stalled the block ~500cy at every barrier-1).
//
// HANG-SAFETY (unchanged): bounded leader collect + unconditional decision
// publish; validation failure -> exact round-0 path. Fast poll has per-step
// budget with sticky fallback to the always-fed agent mailbox.
//
// Worker wid: d = wid>>2 (dir), b = wid&3 (h-quad). Block owns 64 hidden
// units. 512 threads = 8 waves: gate g=w>>1, k-half c=w&1. Each thread holds
// 128 whh weights (row g*256+b*64+L, cols c*128..+128).
// VGPR HISTORY (why 512 threads): 1024-thread blocks cap per-thread VGPRs at
// 128 and the 128 resident weights spill; 8 waves + amdgpu_waves_per_eu(2,2)
// gives a 256-reg budget, residency is cheapest.
// ---------------------------------------------------------------------------
__global__ __launch_bounds__(512)
__attribute__((amdgpu_waves_per_eu(2, 2)))
void lstm_pass(
    const float* __restrict__ xg,   // (2, T, 1024) for this layer
    const float* __restrict__ whh,  // (2, 1024, 256) for this layer
    float* __restrict__ xout,       // (T, 512) concat [hf, hb]
    unsigned long long* __restrict__ pairs,  // agent mailbox (2 dirs, 2 slots, 256)
    unsigned long long* __restrict__ fpairs, // fast (L2) mailbox, same layout
    unsigned long long* __restrict__ rdv)    // 72 slots: [0..63] reports, [64..65] decision
{
    const int tid = threadIdx.x;

    __shared__ __align__(16) float stage[2][256];
    __shared__ float parts[8][64];
    __shared__ int sh_dec[2];

    // ---------------- XCD rendezvous (leader-decided; proven) ----------
    {
        unsigned xcc;
        asm volatile("s_getreg_b32 %0, hwreg(20, 0, 32)" : "=s"(xcc)); // HW_REG_XCC_ID
        xcc &= 0xfu;
        if (tid == 0)
            __hip_atomic_store(rdv + blockIdx.x,
                               (1ull << 32) | (unsigned long long)xcc,
                               __ATOMIC_RELAXED, __HIP_MEMORY_SCOPE_AGENT);

        if (blockIdx.x == 0 && tid < 64) {
            unsigned long long r = 0;
            bool got = false;
            for (int it = 0; it < 32768; ++it) {
                r = __hip_atomic_load(rdv + tid, __ATOMIC_RELAXED,
                                      __HIP_MEMORY_SCOPE_AGENT);
                if (__all((unsigned)(r >> 32) == 1u)) { got = true; break; }
            }
            unsigned long long mask = 0ull;
            if (got) {
                const unsigned x_i = (unsigned)r & 0xfu;
                const unsigned target =
                    (unsigned)__builtin_amdgcn_readfirstlane((int)x_i) & 0xfu;
                bool valid = true;
                unsigned long long mm = 0ull;
                for (unsigned x = 0; x < 8; x++) {
                    unsigned long long m = __ballot(x_i == x);
                    if (__popcll(m) != 8) valid = false;
                    if (x == target) mm = m;
                }
                if (valid) mask = mm;
            }
            if (tid == 0) {
                __hip_atomic_store(rdv + 64, (2ull << 32) | (mask & 0xffffffffull),
                                   __ATOMIC_RELAXED, __HIP_MEMORY_SCOPE_AGENT);
                __hip_atomic_store(rdv + 65, (2ull << 32) | (mask >> 32),
                                   __ATOMIC_RELAXED, __HIP_MEMORY_SCOPE_AGENT);
            }
        }

        if (tid == 0) {
            unsigned long long lo, hi;
            do {
                lo = __hip_atomic_load(rdv + 64, __ATOMIC_RELAXED,
                                       __HIP_MEMORY_SCOPE_AGENT);
            } while ((unsigned)(lo >> 32) != 2u);
            do {
                hi = __hip_atomic_load(rdv + 65, __ATOMIC_RELAXED,
                                       __HIP_MEMORY_SCOPE_AGENT);
            } while ((unsigned)(hi >> 32) != 2u);
            const unsigned long long mask =
                (lo & 0xffffffffull) | ((hi & 0xffffffffull) << 32);
            const int bid = (int)blockIdx.x;
            int fs, wd;
            if (mask != 0ull) {
                fs = 1;
                if ((mask >> bid) & 1ull)
                    wd = __popcll(mask & ((1ull << bid) - 1ull));
                else wd = -1;
            } else {
                fs = 0;
                wd = (bid < 8) ? bid : -1;   // exact round-0 behavior
            }
            sh_dec[0] = fs;
            sh_dec[1] = wd;
        }
        __syncthreads();
    }
    const int fast = sh_dec[0];
    const int wid  = sh_dec[1];
    if (wid < 0) return;   // non-worker blocks free their CU

    const int w = tid >> 6, L = tid & 63;
    const int d = wid >> 2, b = wid & 3;
    const int g = w >> 1, c = w & 1;

    // weight preload: row = g*256 + b*64 + L, cols [c*128, c*128+128)
    float wr[128];
    {
        const float* wp = whh + ((size_t)d << 18) +
                          (size_t)(g * 256 + b * 64 + L) * 256 + c * 128;
#pragma unroll
        for (int i = 0; i < 32; i++) {
            float4 v = ((const float4*)wp)[i];
            wr[4*i+0] = v.x; wr[4*i+1] = v.y; wr[4*i+2] = v.z; wr[4*i+3] = v.w;
        }
    }
    // Defensive: forbid invariant-load remat of the weights.
#pragma unroll
    for (int i = 0; i < 128; i++)
        asm volatile("" : "+v"(wr[i]));

    unsigned long long* mypairs = pairs  + (size_t)d * 512;
    unsigned long long* myfast  = fpairs + (size_t)d * 512;
    const float* xgd = xg + ((size_t)d << 21);

    float cst = 0.f;
    float xgp[4] = {0.f, 0.f, 0.f, 0.f};
    if (w == 7) {
        stage[1][b*64 + L] = 0.f;   // h(0) own chunk for step 1
        int t0 = (d == 0) ? 0 : (T_LEN - 1);
#pragma unroll
        for (int g2 = 0; g2 < 4; g2++)
            xgp[g2] = xgd[((size_t)t0 << 10) + g2*256 + b*64 + L];
    }
    const int pc = (w < 3) ? (w + (w >= b)) : 0;  // probe chunk (remote)

    int healthy = fast;   // sticky per-wave; meaningful only for w<3

    // h broadcast source: lane L holds stage[par][c*128 + 2L], [.. +2L+1]
    // (one ds_read_b64 per wave per step; matvec broadcasts via readlane).
#define RLH(k) __uint_as_float(__builtin_amdgcn_readlane(                    \
        __float_as_uint((((k) & 1) ? hh.y : hh.x)), (k) >> 1))

    for (int s = 1; s <= T_LEN; s++) {
        const int par = s & 1;
        if (w < 3) {
            const int off = ((s-1) & 1) * 256 + pc*64 + L;
            const unsigned tagexp = (unsigned)(s - 1);
            unsigned long long v = 0;
            if (healthy) {
                unsigned long long* ppf = myfast + off;
                int bq = 256;   // per-step budget
                for (;;) {
                    asm volatile(
                        "global_load_dwordx2 %0, %1, off sc0\n\t"
                        "s_waitcnt vmcnt(0)"
                        : "=&v"(v) : "v"((unsigned long long)ppf) : "memory");
                    if (__all((unsigned)(v >> 32) == tagexp)) break;
                    if (--bq == 0) { healthy = 0; break; }
                }
            }
            if (!healthy) {
                unsigned long long* pp = mypairs + off;
                for (;;) {
                    v = __hip_atomic_load(pp, __ATOMIC_RELAXED,
                                          __HIP_MEMORY_SCOPE_AGENT);
                    if (__all((unsigned)(v >> 32) == tagexp)) break;
                }
            }
            stage[par][pc*64 + L] = __uint_as_float((unsigned)v);
        }
        __syncthreads();  // barrier-1: h(s-1) complete in stage[par]

        // w7: issue NEXT step's xg loads now; the matvec below covers the
        // latency before the vmcnt-drain at barrier-2.
        float xgp_nxt[4];
        if (w == 7) {
            int tn = (d == 0) ? ((s < T_LEN) ? s : (T_LEN - 1))
                              : ((s < T_LEN) ? (T_LEN - 1 - s) : 0);
#pragma unroll
            for (int g2 = 0; g2 < 4; g2++)
                xgp_nxt[g2] = xgd[((size_t)tn << 10) + g2*256 + b*64 + L];
        }

        // distribute h across lanes: 2 floats/lane, single ds_read_b64
        float2 hh = *(const float2*)&stage[par][c*128 + 2*L];

        // matvec via readlane broadcast; accumulation order IDENTICAL to the
        // previous ds_read_b128 version (acc[k4&3], in-chain order x,y,z,w).
        float acc[4] = {0.f, 0.f, 0.f, 0.f};
#pragma unroll
        for (int k4 = 0; k4 < 32; k4++) {
            float a = acc[k4 & 3];
            a = fmaf(RLH(4*k4+0), wr[4*k4+0], a);
            a = fmaf(RLH(4*k4+1), wr[4*k4+1], a);
            a = fmaf(RLH(4*k4+2), wr[4*k4+2], a);
            a = fmaf(RLH(4*k4+3), wr[4*k4+3], a);
            acc[k4 & 3] = a;
        }
        parts[w][L] = (acc[0] + acc[1]) + (acc[2] + acc[3]);
        __syncthreads();  // barrier-2 (drain covers xgp_nxt loads)

        if (w == 7) {
            float G[4];
#pragma unroll
            for (int g2 = 0; g2 < 4; g2++)
                G[g2] = parts[2*g2][L] + parts[2*g2+1][L] + xgp[g2];
            float ig = 1.f / (1.f + __expf(-G[0]));
            float fg = 1.f / (1.f + __expf(-G[1]));
            float e2 = __expf(2.f * G[2]);
            float tg = (e2 - 1.f) / (e2 + 1.f);
            float og = 1.f / (1.f + __expf(-G[3]));
            cst = fg * cst + ig * tg;
            float ec = __expf(2.f * cst);
            float th = (ec - 1.f) / (ec + 1.f);
            float h = og * th;
            // publish ASAP (remote blocks are waiting on this)
            const unsigned long long pv =
                ((unsigned long long)(unsigned)s << 32) |
                (unsigned long long)__float_as_uint(h);
            const int poff = par*256 + b*64 + L;
            if (fast) {
                // fast line first (co-located pollers), separate cache line
                asm volatile("global_store_dwordx2 %0, %1, off sc0"
                             :: "v"((unsigned long long)(myfast + poff)),
                                "v"(pv) : "memory");
            }
            // agent mailbox always fed (fallback validity)
            __hip_atomic_store(mypairs + poff, pv,
                               __ATOMIC_RELAXED, __HIP_MEMORY_SCOPE_AGENT);
            stage[1 - par][b*64 + L] = h;   // own chunk for step s+1
            int t = (d == 0) ? (s - 1) : (T_LEN - s);
            xout[(size_t)t * 512 + d*256 + b*64 + L] = h;
#pragma unroll
            for (int g2 = 0; g2 < 4; g2++)
                xgp[g2] = xgp_nxt[g2];
        }
    }
#undef RLH
}

// ---------------------------------------------------------------------------
// feats[t][n] = dot(x2[t], Wout[n]) + bout[n]
// ---------------------------------------------------------------------------
__global__ __launch_bounds__(64) void feats_kern(
    const float* __restrict__ x2, const float* __restrict__ Wout,
    const float* __restrict__ bout, float* __restrict__ feats)
{
    const int t = blockIdx.x;
    __shared__ __align__(16) float xr[512];
    for (int i = threadIdx.x; i < 128; i += 64)
        ((float4*)xr)[i] = ((const float4*)(x2 + (size_t)t * 512))[i];
    __syncthreads();
    const int n = threadIdx.x;
    if (n < K_TAG) {
        const float4* wrow = (const float4*)(Wout + (size_t)n * 512);
        float acc = 0.f;
#pragma unroll 8
        for (int k4 = 0; k4 < 128; k4++) {
            float4 wv = wrow[k4];
            float4 xv = ((const float4*)xr)[k4];
            acc = fmaf(wv.x, xv.x, acc); acc = fmaf(wv.y, xv.y, acc);
            acc = fmaf(wv.z, xv.z, acc); acc = fmaf(wv.w, xv.w, acc);
        }
        feats[t * K_TAG + n] = acc + bout[n];
    }
}

// ---------------------------------------------------------------------------
// Viterbi: single wave. lane n holds fv[n]; trans[n][p] in VGPRs.
// ROUND-3/4 LESSONS: full 48-wide tournament spilled at the default VGPR
// budget (2.7x slower); grouped-8 + amdgpu_waves_per_eu(1,1) (512-reg
// budget, single-wave kernel) fixed it (~700-900us saved, verified round 4).
// ---------------------------------------------------------------------------
__global__ __launch_bounds__(64)
__attribute__((amdgpu_waves_per_eu(1, 1)))
void viterbi_kern(
    const float* __restrict__ feats, const float* __restrict__ trans,
    unsigned char* __restrict__ bptr, int* __restrict__ bnd,
    float* __restrict__ out)
{
    const int lane = threadIdx.x;
    const bool act = lane < K_TAG;
    float tr[K_TAG];
#pragma unroll
    for (int p = 0; p < K_TAG; p++)
        tr[p] = act ? trans[lane * K_TAG + p] : -3.0e38f;

    float fv = (lane == START_TAG) ? 0.f : NEG_VAL;
    int orig = lane;
    float feat = act ? feats[lane] : 0.f;

    for (int t = 0; t < T_LEN; t++) {
        float featn = (act && (t + 1 < T_LEN)) ? feats[(t + 1) * K_TAG + lane] : 0.f;

        // 6 groups of 8, each reduced serially (ascending, strict > keeps
        // first max); groups are independent -> chains interleave.
        float gm[6]; int gb[6];
#pragma unroll
        for (int q = 0; q < 6; q++) {
            float m = __uint_as_float(
                __builtin_amdgcn_readlane(__float_as_uint(fv), 8*q)) + tr[8*q];
            int bp = 8*q;
#pragma unroll
            for (int j = 1; j < 8; j++) {
                float sc = __uint_as_float(
                    __builtin_amdgcn_readlane(__float_as_uint(fv), 8*q+j)) + tr[8*q+j];
                if (sc > m) { m = sc; bp = 8*q + j; }
            }
            gm[q] = m; gb[q] = bp;
        }
        float m = gm[0]; int bp = gb[0];
#pragma unroll
        for (int q = 1; q < 6; q++)
            if (gm[q] > m) { m = gm[q]; bp = gb[q]; }

        fv = m + feat;
        feat = featn;
        if (act) bptr[t * K_TAG + lane] = (unsigned char)bp;
        orig = __shfl(orig, bp);
        if ((t & 127) == 127) {
            if (act) bnd[(t >> 7) * K_TAG + lane] = orig;
            orig = lane;
        }
    }
    float term = fv + (act ? trans[END_TAG * K_TAG + lane] : -3.0e38f);
    float bm = -3.0e38f; int bl = 0;
#pragma unroll
    for (int p = 0; p < K_TAG; p++) {
        float v = __uint_as_float(__builtin_amdgcn_readlane(__float_as_uint(term), p));
        if (v > bm) { bm = v; bl = p; }
    }
    if (lane == 0) out[0] = bm;

    __shared__ int sb[16];
    if (lane == 0) {
        int s = bl;
        sb[15] = s;
        for (int k = 15; k >= 1; k--) { s = bnd[k * K_TAG + s]; sb[k - 1] = s; }
    }
    __syncthreads();
    if (lane < 16) {
        int s = sb[lane];
        for (int t = lane * 128 + 127; t >= lane * 128; t--) {
            out[1 + t] = (float)s;
            s = (int)bptr[t * K_TAG + s];
        }
    }
}

// ---------------------------------------------------------------------------
extern "C" void kernel_launch(void* const* d_in, const int* in_sizes, int n_in,
                              void* d_out, int out_size, void* d_ws, size_t ws_size,
                              hipStream_t stream) {
    const int*   sent = (const int*)d_in[0];
    const float* emb  = (const float*)d_in[1];
    const float* wih  = (const float*)d_in[2];   // (2,2,1024,512)
    const float* whh  = (const float*)d_in[3];   // (2,2,1024,256)
    const float* bih  = (const float*)d_in[4];   // (2,2,1024)
    const float* bhh  = (const float*)d_in[5];
    const float* Wout = (const float*)d_in[6];   // (48,512)
    const float* bout = (const float*)d_in[7];   // (48,)
    const float* trans= (const float*)d_in[8];   // (48,48)
    float* out = (float*)d_out;

    float* ws = (float*)d_ws;
    float* xg    = ws;                       // 2*2048*1024 = 4194304 floats
    float* x1    = xg + 4194304;             // 2048*512
    float* x2    = x1 + 1048576;             // 2048*512
    float* feats = x2 + 1048576;             // 2048*48 = 98304
    unsigned long long* pairs = (unsigned long long*)(feats + 98304); // 2 layers * 1024
    unsigned char* bptr = (unsigned char*)(pairs + 2048);             // 2048*48 bytes
    int* bnd = (int*)(bptr + T_LEN * K_TAG);                          // 16*48 ints
    // rdv (2 layers x 72 slots) and fpairs (2 layers x 1024 slots) OVERLAY
    // the head of bptr: bptr is written only by viterbi_kern, which runs
    // after both lstm passes — no lifetime overlap, zero ws growth.
    unsigned long long* rdv    = (unsigned long long*)bptr;           // 144 slots
    unsigned long long* fpairs = (unsigned long long*)bptr + 256;     // 2048 slots

    // zero sync tags + rendezvous + fast mailbox (ws is poisoned 0xAA before
    // every timed launch)
    hipMemsetAsync(pairs, 0, 2048 * sizeof(unsigned long long), stream);
    hipMemsetAsync(bptr,  0, 2304 * sizeof(unsigned long long), stream);

    dim3 gg(32, 32);
    // layer 1: xg = gather(emb,sent) @ wih[0,*].T + bias
    gemm_xg<<<gg, 256, 0, stream>>>(emb, sent, wih, bih, bhh, xg, 1);
    lstm_pass<<<64, 512, 0, stream>>>(xg, whh, x1, pairs, fpairs, rdv);
    // layer 2
    gemm_xg<<<gg, 256, 0, stream>>>(x1, nullptr, wih + (1 << 20),
                                    bih + 2048, bhh + 2048, xg, 0);
    lstm_pass<<<64, 512, 0, stream>>>(xg, whh + (1 << 19), x2,
                                      pairs + 1024, fpairs + 1024, rdv + 72);
    // projection + viterbi
    feats_kern<<<T_LEN, 64, 0, stream>>>(x2, Wout, bout, feats);
    viterbi_kern<<<1, 64, 0, stream>>>(feats, trans, bptr, bnd, out);
}